// Round 9
// baseline (2405.996 us; speedup 1.0000x reference)
//
#include <hip/hip_runtime.h>
#include <math.h>

// LSTM persistent kernel, R9: MFMA matvec. One block per batch (64 blocks),
// 512 threads = 8 waves.
//
// R8 post-mortem: VALU is exhausted -- fp32 fma, pk_fma_f32, and fdot2 all
// issue 2 MAC/lane per 4cy, so the 512x128 matvec is pinned at 512
// cy/SIMD/step on the vector pipe no matter the dtype (R1/R4/R5/R8 all
// ~1.9-2.1ms). Only the matrix pipe breaks that: 32x mfma_f32_16x16x32_f16
// per step = ~155 cy/SIMD.
//
// Layout: wave w owns gate-row tiles 4w..4w+3 (16 rows each). A-frag =
// Mk-scaled W_hh f16 (A[m=lane&15][k=(lane>>4)*8+j], 64 VGPRs, static).
// B-frag = h replicated across all 16 cols: every lane reads h[32c+8p+j]
// (broadcast; result independent of B's n-mapping). D cols all equal W.h;
// lanes m==0 hold rows 16t+4p+{0..3} in d[0..3] -> ds_write_b128 into a
// 136-stride preact buffer. Tail = R5's proven per-element code (quad owns
// element, lane q = gate q), 1 preact each, DPP gate broadcast, c/h local.
constexpr int Hdim = 128;
constexpr int TMAX = 4096;

typedef _Float16 v8h __attribute__((ext_vector_type(8)));
typedef float v4f __attribute__((ext_vector_type(4)));

template <int CTRL>
__device__ __forceinline__ float dppf(float v) {
  return __int_as_float(
      __builtin_amdgcn_update_dpp(0, __float_as_int(v), CTRL, 0xF, 0xF, true));
}

#if __has_builtin(__builtin_amdgcn_exp2f)
__device__ __forceinline__ float exp2_fast(float x) {
  return __builtin_amdgcn_exp2f(x);
}
#else
__device__ __forceinline__ float exp2_fast(float x) {
  return __expf(x * 0.6931471805599453f);
}
#endif

__global__ __launch_bounds__(512) void lstm_mfma(
    const float* __restrict__ data, const float* __restrict__ h0,
    const float* __restrict__ c0, const float* __restrict__ W_ih,
    const float* __restrict__ W_hh, const float* __restrict__ b_ih,
    const float* __restrict__ b_hh, const float* __restrict__ W_out,
    const float* __restrict__ b_out, float* __restrict__ out, int T) {
  __shared__ __align__(16) float xs[TMAX];
  __shared__ __align__(16) _Float16 hbuf[2][Hdim];
  __shared__ __align__(16) float pre[4 * 136];  // gate g at 136*g, pad kills
                                                // the 128-stride quad conflict

  const int b = blockIdx.x;
  const int tid = threadIdx.x;
  const int lane = tid & 63;
  const int wv = tid >> 6;   // wave 0..7
  const int p = lane >> 4;   // 0..3
  const int m = lane & 15;   // row-in-tile
  const int q = tid & 3;     // tail: gate index
  const int e = tid >> 2;    // tail: element 0..127

  // Stage input row (coalesced float4).
  {
    const float4* src = (const float4*)(data + (size_t)b * T);
    float4* dst = (float4*)xs;
    for (int i = tid; i < T / 4; i += 512) dst[i] = src[i];
  }

  constexpr float L2E = 1.44269504088896f;

  // A-frags: tile i -> global tile t4=4*wv+i (gate rows [16*t4,16*t4+16)),
  // chunk c -> k in [32c,32c+32). Lane holds A[m][32c + 8p + j], j=0..7,
  // pre-scaled by Mk(gate) (commutes with the k-sum).
  v8h a[4][4];
#pragma unroll
  for (int i = 0; i < 4; ++i) {
    const int row = 16 * (4 * wv + i) + m;
    const float Mr = ((row >> 7) == 2) ? 2.0f * L2E : -L2E;
    const float* wr = W_hh + (size_t)row * Hdim + 8 * p;
#pragma unroll
    for (int c = 0; c < 4; ++c) {
      float4 v0 = ((const float4*)(wr + 32 * c))[0];
      float4 v1 = ((const float4*)(wr + 32 * c))[1];
      a[i][c] = v8h{(_Float16)(Mr * v0.x), (_Float16)(Mr * v0.y),
                    (_Float16)(Mr * v0.z), (_Float16)(Mr * v0.w),
                    (_Float16)(Mr * v1.x), (_Float16)(Mr * v1.y),
                    (_Float16)(Mr * v1.z), (_Float16)(Mr * v1.w)};
    }
  }

  // Tail lane-constants for gate q (0=i,1=f,2=g,3=o), Mk pre-folded.
  const int rowt = e + 128 * q;
  const float MkL = (q == 2) ? 2.0f * L2E : -L2E;
  const float wihL = MkL * W_ih[rowt];
  const float bsL = MkL * (b_ih[rowt] + b_hh[rowt]);
  const float As = (q == 2) ? -2.0f : 1.0f;
  const float Bs = (q == 2) ? 1.0f : 0.0f;

  float cst = c0[(size_t)b * Hdim + e];
  if (q == 0) hbuf[0][e] = (_Float16)h0[(size_t)b * Hdim + e];
  __syncthreads();

#pragma unroll 2
  for (int t = 0; t < T; ++t) {
    // B-frags: h chunk c, lane value h[32c + 8p + j] (16-lane broadcast,
    // 16B aligned ds_read_b128). Same for every wave.
    const _Float16* hb = hbuf[t & 1];
    v8h bq[4];
#pragma unroll
    for (int c = 0; c < 4; ++c)
      bq[c] = *(const v8h*)(hb + 32 * c + 8 * p);

    // 4 independent tile chains x 4 chained k-steps.
    v4f d[4];
#pragma unroll
    for (int i = 0; i < 4; ++i) {
      v4f acc = {0.f, 0.f, 0.f, 0.f};
#pragma unroll
      for (int c = 0; c < 4; ++c)
        acc = __builtin_amdgcn_mfma_f32_16x16x32_f16(a[i][c], bq[c], acc,
                                                     0, 0, 0);
      d[i] = acc;
    }

    // Scatter: lane m==0 of each p-group holds rows 16*t4+4p+{0..3} (all
    // D cols equal; col layout row=(lane>>4)*4+reg). 4 lanes x 4 b128.
    if (m == 0) {
#pragma unroll
      for (int i = 0; i < 4; ++i) {
        const int rowbase = 16 * (4 * wv + i);
        const int addr = 136 * (rowbase >> 7) + (rowbase & 127) + 4 * p;
        *(float4*)&pre[addr] = float4{d[i].x, d[i].y, d[i].z, d[i].w};
      }
    }
    const float xt = xs[t];
    __syncthreads();

    // Tail: quad owns element e, lane q reads gate q's preact.
    const float z = pre[136 * q + e];
    const float pg = fmaf(xt, wihL, bsL) + z;
    const float y = fmaf(As, __builtin_amdgcn_rcpf(1.0f + exp2_fast(pg)), Bs);

    const float yi = dppf<0x00>(y);
    const float yf = dppf<0x55>(y);
    const float yg = dppf<0xAA>(y);
    const float yo = dppf<0xFF>(y);

    cst = fmaf(yf, cst, yi * yg);
    const float th = fmaf(
        -2.0f, __builtin_amdgcn_rcpf(1.0f + exp2_fast(cst * (2.0f * L2E))),
        1.0f);
    const float h = yo * th;

    if (q == 0) hbuf[(t + 1) & 1][e] = (_Float16)h;
    __syncthreads();
  }

  // Final linear: out[b] = h_T . W_out + b_out (wave 0).
  if (tid < 64) {
    const _Float16* hf = hbuf[T & 1];
    float sum =
        (float)hf[tid] * W_out[tid] + (float)hf[tid + 64] * W_out[tid + 64];
#pragma unroll
    for (int off = 32; off > 0; off >>= 1) sum += __shfl_down(sum, off, 64);
    if (tid == 0) out[b] = sum + b_out[0];
  }
}

extern "C" void kernel_launch(void* const* d_in, const int* in_sizes, int n_in,
                              void* d_out, int out_size, void* d_ws,
                              size_t ws_size, hipStream_t stream) {
  const float* data = (const float*)d_in[0];
  const float* h0 = (const float*)d_in[1];
  const float* c0 = (const float*)d_in[2];
  const float* W_ih = (const float*)d_in[3];
  const float* W_hh = (const float*)d_in[4];
  const float* b_ih = (const float*)d_in[5];
  const float* b_hh = (const float*)d_in[6];
  const float* W_out = (const float*)d_in[7];
  const float* b_out = (const float*)d_in[8];
  float* out = (float*)d_out;

  const int B = in_sizes[1] / Hdim;  // 64
  const int T = in_sizes[0] / B;     // 4096

  lstm_mfma<<<B, 512, 0, stream>>>(data, h0, c0, W_ih, W_hh, b_ih, b_hh,
                                   W_out, b_out, out, T);
}

// Round 10
// 1885.257 us; speedup vs baseline: 1.2762x; 1.2762x over previous
//
#include <hip/hip_runtime.h>
#include <math.h>

// LSTM persistent kernel, R10: MFMA matvec with IN-WAVE tail. One block per
// batch (64 blocks), 512 threads = 8 waves.
//
// R9 was critical-path-bound (1409 cy/step): D scattered to LDS, mid
// barrier, re-read, DPP tail -> a full LDS round-trip per step. R10
// re-tiles so wave wv owns ALL FOUR GATES of elements 16wv..16wv+15
// (tiles at rows 128g+16wv, g=0..3). After 16 MFMAs the lane's d[g] regs
// hold gates i,f,g,o for elements 16wv+4p+{0..3} (D: row=4p+reg, all cols
// equal) -> 3-cndmask select by m&3 gives each lane one element's 4 gates
// -> activation + c/h update fully in-wave; lanes m<4 write h; ONE barrier
// per step. ~125 VGPR working set fits the default budget (no spill).
constexpr int Hdim = 128;
constexpr int TMAX = 4096;

typedef _Float16 v8h __attribute__((ext_vector_type(8)));
typedef float v4f __attribute__((ext_vector_type(4)));

#if __has_builtin(__builtin_amdgcn_exp2f)
__device__ __forceinline__ float exp2_fast(float x) {
  return __builtin_amdgcn_exp2f(x);
}
#else
__device__ __forceinline__ float exp2_fast(float x) {
  return __expf(x * 0.6931471805599453f);
}
#endif

__device__ __forceinline__ float sel4(v4f d, int r) {
  const float s01 = (r & 1) ? d.y : d.x;
  const float s23 = (r & 1) ? d.w : d.z;
  return (r & 2) ? s23 : s01;
}

__global__ __launch_bounds__(512) void lstm_mfma(
    const float* __restrict__ data, const float* __restrict__ h0,
    const float* __restrict__ c0, const float* __restrict__ W_ih,
    const float* __restrict__ W_hh, const float* __restrict__ b_ih,
    const float* __restrict__ b_hh, const float* __restrict__ W_out,
    const float* __restrict__ b_out, float* __restrict__ out, int T) {
  __shared__ __align__(16) float xs[TMAX];
  __shared__ __align__(16) _Float16 hbuf[2][Hdim];

  const int b = blockIdx.x;
  const int tid = threadIdx.x;
  const int lane = tid & 63;
  const int wv = tid >> 6;  // wave 0..7 owns elements 16wv..16wv+15
  const int p = lane >> 4;  // 0..3
  const int m = lane & 15;  // row-in-tile / col id
  const int r = m & 3;      // which d-reg this lane's tail handles
  const int el = 16 * wv + 4 * p + r;  // my tail element (copies for m>=4)

  // Stage input row (coalesced float4).
  {
    const float4* src = (const float4*)(data + (size_t)b * T);
    float4* dst = (float4*)xs;
    for (int i = tid; i < T / 4; i += 512) dst[i] = src[i];
  }

  constexpr float L2E = 1.44269504088896f;

  // A-frags: gate g -> rows [128g+16wv, 128g+16wv+16), chunk c -> k in
  // [32c,32c+32). Lane holds A[m][32c+8p+j], j=0..7, pre-scaled by Mk(g).
  v8h a[4][4];
#pragma unroll
  for (int g = 0; g < 4; ++g) {
    const int row = 128 * g + 16 * wv + m;
    const float Mr = (g == 2) ? 2.0f * L2E : -L2E;
    const float* wr = W_hh + (size_t)row * Hdim + 8 * p;
#pragma unroll
    for (int c = 0; c < 4; ++c) {
      float4 v0 = ((const float4*)(wr + 32 * c))[0];
      float4 v1 = ((const float4*)(wr + 32 * c))[1];
      a[g][c] = v8h{(_Float16)(Mr * v0.x), (_Float16)(Mr * v0.y),
                    (_Float16)(Mr * v0.z), (_Float16)(Mr * v0.w),
                    (_Float16)(Mr * v1.x), (_Float16)(Mr * v1.y),
                    (_Float16)(Mr * v1.z), (_Float16)(Mr * v1.w)};
    }
  }

  // Tail constants for my element, per gate (Mk pre-folded).
  float wih[4], bs[4];
#pragma unroll
  for (int g = 0; g < 4; ++g) {
    const float Mr = (g == 2) ? 2.0f * L2E : -L2E;
    const int row = 128 * g + el;
    wih[g] = Mr * W_ih[row];
    bs[g] = Mr * (b_ih[row] + b_hh[row]);
  }

  float cst = c0[(size_t)b * Hdim + el];
  if (tid < 128) hbuf[0][tid] = (_Float16)h0[(size_t)b * Hdim + tid];
  __syncthreads();

#pragma unroll 2
  for (int t = 0; t < T; ++t) {
    // B-frags: h chunk c, lane reads h[32c+8p+j] (16-lane broadcast).
    const _Float16* hb = hbuf[t & 1];
    v8h bq[4];
#pragma unroll
    for (int c = 0; c < 4; ++c) bq[c] = *(const v8h*)(hb + 32 * c + 8 * p);
    const float xt = xs[t];

    // 4 independent gate-tile chains x 4 chained k-steps.
    v4f d[4];
#pragma unroll
    for (int g = 0; g < 4; ++g) {
      v4f acc = {0.f, 0.f, 0.f, 0.f};
#pragma unroll
      for (int c = 0; c < 4; ++c)
        acc = __builtin_amdgcn_mfma_f32_16x16x32_f16(a[g][c], bq[c], acc,
                                                     0, 0, 0);
      d[g] = acc;
    }

    // In-wave tail: my element's 4 gate preacts via reg-select by r.
    const float zi = sel4(d[0], r);
    const float zf = sel4(d[1], r);
    const float zg = sel4(d[2], r);
    const float zo = sel4(d[3], r);

    const float yi =
        __builtin_amdgcn_rcpf(1.0f + exp2_fast(fmaf(xt, wih[0], bs[0]) + zi));
    const float yf =
        __builtin_amdgcn_rcpf(1.0f + exp2_fast(fmaf(xt, wih[1], bs[1]) + zf));
    const float yg = fmaf(
        -2.0f,
        __builtin_amdgcn_rcpf(1.0f + exp2_fast(fmaf(xt, wih[2], bs[2]) + zg)),
        1.0f);
    const float yo =
        __builtin_amdgcn_rcpf(1.0f + exp2_fast(fmaf(xt, wih[3], bs[3]) + zo));

    cst = fmaf(yf, cst, yi * yg);
    const float th = fmaf(
        -2.0f, __builtin_amdgcn_rcpf(1.0f + exp2_fast(cst * (2.0f * L2E))),
        1.0f);
    const float h = yo * th;

    if (m < 4) hbuf[(t + 1) & 1][el] = (_Float16)h;
    __syncthreads();
  }

  // Final linear: out[b] = h_T . W_out + b_out (wave 0).
  if (tid < 64) {
    const _Float16* hf = hbuf[T & 1];
    float sum =
        (float)hf[tid] * W_out[tid] + (float)hf[tid + 64] * W_out[tid + 64];
#pragma unroll
    for (int off = 32; off > 0; off >>= 1) sum += __shfl_down(sum, off, 64);
    if (tid == 0) out[b] = sum + b_out[0];
  }
}

extern "C" void kernel_launch(void* const* d_in, const int* in_sizes, int n_in,
                              void* d_out, int out_size, void* d_ws,
                              size_t ws_size, hipStream_t stream) {
  const float* data = (const float*)d_in[0];
  const float* h0 = (const float*)d_in[1];
  const float* c0 = (const float*)d_in[2];
  const float* W_ih = (const float*)d_in[3];
  const float* W_hh = (const float*)d_in[4];
  const float* b_ih = (const float*)d_in[5];
  const float* b_hh = (const float*)d_in[6];
  const float* W_out = (const float*)d_in[7];
  const float* b_out = (const float*)d_in[8];
  float* out = (float*)d_out;

  const int B = in_sizes[1] / Hdim;  // 64
  const int T = in_sizes[0] / B;     // 4096

  lstm_mfma<<<B, 512, 0, stream>>>(data, h0, c0, W_ih, W_hh, b_ih, b_hh,
                                   W_out, b_out, out, T);
}